// Round 1
// baseline (12518.250 us; speedup 1.0000x reference)
//
#include <hip/hip_runtime.h>
#include <cmath>

#define NHID 1024
#define NTOK 10000
#define TT 128
#define BB 32
#define BN (BB*NHID)            // 32768 elems per (B,NHID) state
#define WMAT (2048*1024)        // elems per transposed weight matrix

typedef __attribute__((ext_vector_type(8))) short s8v;   // 8 x bf16 raw
typedef __attribute__((ext_vector_type(4))) float f4v;   // MFMA accumulator

#define MFMA(a,b,c) __builtin_amdgcn_mfma_f32_16x16x32_bf16(a,b,c,0,0,0)

__device__ __forceinline__ float sigf(float x){ return 1.f/(1.f+__expf(-x)); }
__device__ __forceinline__ float actf(int a, float h){
  switch(a){ case 0: return sigf(h); case 1: return fmaxf(h,0.f);
             case 2: return tanhf(h); default: return h; }
}
__device__ __forceinline__ unsigned short f2bf(float x){
  union { float f; unsigned u; } v; v.f = x;
  unsigned r = v.u + 0x7fffu + ((v.u >> 16) & 1u);
  return (unsigned short)(r >> 16);
}

// ---------------- prep kernels ----------------

// Transpose+convert 10 (1024 x 2048) f32 matrices -> (2048 x 1024) bf16.
// z=0: W0 rows 0..1023 ; z=1: W0 rows 1024..2047 ; z=2..9: Ws[0..7]
__global__ __launch_bounds__(256) void k_transpose_cvt(
    const float* __restrict__ W0, const float* __restrict__ Ws,
    unsigned short* __restrict__ dstAll)
{
  int z = blockIdx.z;
  const float* src = (z==0) ? W0 : (z==1) ? (W0 + (size_t)1024*2048)
                                          : (Ws + (size_t)(z-2)*1024*2048);
  unsigned short* dst = dstAll + (size_t)z*WMAT;
  __shared__ float tile[32][33];
  int n0 = blockIdx.x*32;           // src col (0..2047)
  int k0 = blockIdx.y*32;           // src row (0..1023)
  int tx = threadIdx.x & 31, ty = threadIdx.x >> 5;
  #pragma unroll
  for (int i=0;i<4;i++){
    int k = k0 + ty + i*8;
    tile[ty + i*8][tx] = src[(size_t)k*2048 + n0 + tx];
  }
  __syncthreads();
  #pragma unroll
  for (int i=0;i<4;i++){
    int n = n0 + ty + i*8;
    dst[(size_t)n*1024 + k0 + tx] = f2bf(tile[tx][ty + i*8]);
  }
}

__global__ void k_cvt(const float* __restrict__ src, unsigned short* __restrict__ dst, int n){
  int i = blockIdx.x*blockDim.x + threadIdx.x;
  int stride = gridDim.x*blockDim.x;
  for (; i < n; i += stride) dst[i] = f2bf(src[i]);
}

// ---------------- recurrence kernels (1 wave per block, 16 output cols) ---------

// s0 = hp + sig(c0)*(tanh(h0)-hp), [c0|h0] = [x,h] @ W0.  K=2048 split x|h.
__global__ __launch_bounds__(64) void k_init(
    const int* __restrict__ tok_t, const unsigned short* __restrict__ encw_bf,
    const unsigned short* __restrict__ Wt,
    const unsigned short* __restrict__ hprev_bf, const float* __restrict__ hprev_f,
    float* __restrict__ st_f, unsigned short* __restrict__ st_bf)
{
  int lane = threadIdx.x;
  int q = lane >> 4, r = lane & 15;
  int j0 = blockIdx.x * 16;
  f4v z = {0.f,0.f,0.f,0.f};
  f4v aC0=z, aC1=z, aH0=z, aH1=z;
  int t0 = tok_t[r], t1 = tok_t[16 + r];
  const s8v* ax0 = (const s8v*)(encw_bf + (size_t)t0*NHID);
  const s8v* ax1 = (const s8v*)(encw_bf + (size_t)t1*NHID);
  const s8v* ah0 = (const s8v*)(hprev_bf + (size_t)r*NHID);
  const s8v* ah1 = (const s8v*)(hprev_bf + (size_t)(16+r)*NHID);
  const s8v* bc0 = (const s8v*)(Wt + (size_t)(j0 + r)*1024);
  const s8v* bh0 = (const s8v*)(Wt + (size_t)(1024 + j0 + r)*1024);
  const s8v* bc1 = (const s8v*)(Wt + (size_t)WMAT + (size_t)(j0 + r)*1024);
  const s8v* bh1 = (const s8v*)(Wt + (size_t)WMAT + (size_t)(1024 + j0 + r)*1024);
  #pragma unroll 4
  for (int v = q; v < 128; v += 4) {
    s8v a0 = ax0[v], a1 = ax1[v], bc = bc0[v], bh = bh0[v];
    aC0 = MFMA(a0, bc, aC0); aC1 = MFMA(a1, bc, aC1);
    aH0 = MFMA(a0, bh, aH0); aH1 = MFMA(a1, bh, aH1);
  }
  #pragma unroll 4
  for (int v = q; v < 128; v += 4) {
    s8v a0 = ah0[v], a1 = ah1[v], bc = bc1[v], bh = bh1[v];
    aC0 = MFMA(a0, bc, aC0); aC1 = MFMA(a1, bc, aC1);
    aH0 = MFMA(a0, bh, aH0); aH1 = MFMA(a1, bh, aH1);
  }
  int col = j0 + r;
  #pragma unroll
  for (int mi=0; mi<2; mi++){
    f4v c4 = mi ? aC1 : aC0, h4 = mi ? aH1 : aH0;
    #pragma unroll
    for (int t4=0; t4<4; t4++){
      int brow = mi*16 + q*4 + t4;
      float hp = hprev_f[brow*NHID + col];
      float v = hp + sigf(c4[t4])*(tanhf(h4[t4]) - hp);
      st_f[brow*NHID + col] = v;
      st_bf[brow*NHID + col] = f2bf(v);
    }
  }
}

// generic edges: up to 3 per launch, 64 blocks each. act: 0 sig,1 relu,2 tanh,3 id
__global__ __launch_bounds__(64) void k_edges(
    const unsigned short* __restrict__ Wt,
    float* __restrict__ st_f, unsigned short* __restrict__ st_bf,
    int e0,int p0,int a0, int e1,int p1,int a1, int e2,int p2,int a2)
{
  int slot = blockIdx.x >> 6;
  int e,p,a;
  if (slot==0){e=e0;p=p0;a=a0;} else if (slot==1){e=e1;p=p1;a=a1;} else {e=e2;p=p2;a=a2;}
  int lane = threadIdx.x;
  int q = lane >> 4, r = lane & 15;
  int j0 = (blockIdx.x & 63) * 16;
  const unsigned short* W = Wt + (size_t)(e+2)*WMAT;
  const unsigned short* spb = st_bf + (size_t)p*BN;
  const float* spf = st_f + (size_t)p*BN;
  f4v z = {0.f,0.f,0.f,0.f};
  f4v aC0=z, aC1=z, aH0=z, aH1=z;
  const s8v* a0p = (const s8v*)(spb + (size_t)r*NHID);
  const s8v* a1p = (const s8v*)(spb + (size_t)(16+r)*NHID);
  const s8v* bcp = (const s8v*)(W + (size_t)(j0 + r)*1024);
  const s8v* bhp = (const s8v*)(W + (size_t)(1024 + j0 + r)*1024);
  #pragma unroll 4
  for (int v = q; v < 128; v += 4) {
    s8v a0 = a0p[v], a1 = a1p[v], bc = bcp[v], bh = bhp[v];
    aC0 = MFMA(a0, bc, aC0); aC1 = MFMA(a1, bc, aC1);
    aH0 = MFMA(a0, bh, aH0); aH1 = MFMA(a1, bh, aH1);
  }
  float* sof = st_f + (size_t)(e+1)*BN;
  unsigned short* sob = st_bf + (size_t)(e+1)*BN;
  int col = j0 + r;
  #pragma unroll
  for (int mi=0; mi<2; mi++){
    f4v c4 = mi ? aC1 : aC0, h4 = mi ? aH1 : aH0;
    #pragma unroll
    for (int t4=0; t4<4; t4++){
      int brow = mi*16 + q*4 + t4;
      float sp = spf[brow*NHID + col];
      float v = sp + sigf(c4[t4])*(actf(a, h4[t4]) - sp);
      sof[brow*NHID + col] = v;
      sob[brow*NHID + col] = f2bf(v);
    }
  }
}

// final level: e5 (sigmoid) and e7 (relu), both pred s5; fuse mean of s1..s8.
__global__ __launch_bounds__(64) void k_last(
    const unsigned short* __restrict__ Wt,
    const float* __restrict__ st_f, const unsigned short* __restrict__ st_bf,
    float* __restrict__ hout_f, unsigned short* __restrict__ hout_bf)
{
  int lane = threadIdx.x;
  int q = lane >> 4, r = lane & 15;
  int j0 = blockIdx.x * 16;
  const unsigned short* spb = st_bf + (size_t)5*BN;
  const float* spf = st_f + (size_t)5*BN;
  const unsigned short* W5 = Wt + (size_t)7*WMAT;   // edge 5 -> z=7
  const unsigned short* W7 = Wt + (size_t)9*WMAT;   // edge 7 -> z=9
  f4v z = {0.f,0.f,0.f,0.f};
  f4v c50=z,c51=z,h50=z,h51=z,c70=z,c71=z,h70=z,h71=z;
  const s8v* a0p = (const s8v*)(spb + (size_t)r*NHID);
  const s8v* a1p = (const s8v*)(spb + (size_t)(16+r)*NHID);
  const s8v* b5c = (const s8v*)(W5 + (size_t)(j0 + r)*1024);
  const s8v* b5h = (const s8v*)(W5 + (size_t)(1024 + j0 + r)*1024);
  const s8v* b7c = (const s8v*)(W7 + (size_t)(j0 + r)*1024);
  const s8v* b7h = (const s8v*)(W7 + (size_t)(1024 + j0 + r)*1024);
  #pragma unroll 2
  for (int v = q; v < 128; v += 4) {
    s8v a0 = a0p[v], a1 = a1p[v];
    s8v bc5 = b5c[v], bh5 = b5h[v], bc7 = b7c[v], bh7 = b7h[v];
    c50 = MFMA(a0, bc5, c50); c51 = MFMA(a1, bc5, c51);
    h50 = MFMA(a0, bh5, h50); h51 = MFMA(a1, bh5, h51);
    c70 = MFMA(a0, bc7, c70); c71 = MFMA(a1, bc7, c71);
    h70 = MFMA(a0, bh7, h70); h71 = MFMA(a1, bh7, h71);
  }
  int col = j0 + r;
  #pragma unroll
  for (int mi=0; mi<2; mi++){
    f4v c5 = mi ? c51 : c50, h5 = mi ? h51 : h50;
    f4v c7 = mi ? c71 : c70, h7 = mi ? h71 : h70;
    #pragma unroll
    for (int t4=0; t4<4; t4++){
      int brow = mi*16 + q*4 + t4;
      int off = brow*NHID + col;
      float s5j = spf[off];
      float s6 = s5j + sigf(c5[t4])*(sigf(h5[t4]) - s5j);
      float s8 = s5j + sigf(c7[t4])*(fmaxf(h7[t4],0.f) - s5j);
      float sum = st_f[(size_t)1*BN + off] + st_f[(size_t)2*BN + off]
                + st_f[(size_t)3*BN + off] + st_f[(size_t)4*BN + off]
                + s5j + s6 + st_f[(size_t)7*BN + off] + s8;
      float hn = 0.125f * sum;
      hout_f[off] = hn;
      hout_bf[off] = f2bf(hn);
    }
  }
}

// ---------------- decoder ----------------

// logits(4096 x 10000) = H_bf(4096 x 1024) @ encW_bf(10000 x 1024)^T, f32 out (no bias)
__global__ __launch_bounds__(256) void k_decoder(
    const unsigned short* __restrict__ Hb, const unsigned short* __restrict__ Wb,
    float* __restrict__ out)
{
  int wave = threadIdx.x >> 6, lane = threadIdx.x & 63;
  int q = lane >> 4, r = lane & 15;
  int bm = blockIdx.y*64 + (wave>>1)*32;
  int bn = blockIdx.x*64 + (wave&1)*32;
  f4v z = {0.f,0.f,0.f,0.f};
  f4v acc00=z, acc01=z, acc10=z, acc11=z;
  const s8v* a0p = (const s8v*)(Hb + (size_t)(bm + r)*NHID);
  const s8v* a1p = (const s8v*)(Hb + (size_t)(bm + 16 + r)*NHID);
  int n0 = bn + r, n1 = bn + 16 + r;
  const s8v* b0p = (const s8v*)(Wb + (size_t)(n0 < NTOK ? n0 : 0)*NHID);
  const s8v* b1p = (const s8v*)(Wb + (size_t)(n1 < NTOK ? n1 : 0)*NHID);
  #pragma unroll 4
  for (int v = q; v < 128; v += 4) {
    s8v a0 = a0p[v], a1 = a1p[v], b0 = b0p[v], b1 = b1p[v];
    acc00 = MFMA(a0, b0, acc00); acc10 = MFMA(a1, b0, acc10);
    acc01 = MFMA(a0, b1, acc01); acc11 = MFMA(a1, b1, acc11);
  }
  #pragma unroll
  for (int ni=0; ni<2; ni++){
    int col = bn + ni*16 + r;
    if (col >= NTOK) continue;
    #pragma unroll
    for (int mi=0; mi<2; mi++){
      f4v a = (mi==0) ? (ni==0 ? acc00 : acc01) : (ni==0 ? acc10 : acc11);
      #pragma unroll
      for (int t4=0; t4<4; t4++){
        int row = bm + mi*16 + q*4 + t4;
        out[(size_t)row*NTOK + col] = a[t4];
      }
    }
  }
}

// in-place log_softmax over rows of 10000, adding bias first
__global__ __launch_bounds__(256) void k_logsoftmax(
    float* __restrict__ logits, const float* __restrict__ bias)
{
  size_t row = blockIdx.x;
  float* p = logits + row * NTOK;
  float v[40];
  float mx = -1e30f;
  #pragma unroll
  for (int i=0;i<40;i++){
    int c = threadIdx.x + (i<<8);
    float x = (c < NTOK) ? (p[c] + bias[c]) : -1e30f;
    v[i] = x; mx = fmaxf(mx, x);
  }
  #pragma unroll
  for (int off=32; off>0; off>>=1) mx = fmaxf(mx, __shfl_down(mx, off));
  __shared__ float red[4], red2[4];
  int wv = threadIdx.x>>6, ln = threadIdx.x&63;
  if (ln==0) red[wv] = mx;
  __syncthreads();
  mx = fmaxf(fmaxf(red[0],red[1]), fmaxf(red[2],red[3]));
  float s = 0.f;
  #pragma unroll
  for (int i=0;i<40;i++) s += __expf(v[i] - mx);
  #pragma unroll
  for (int off=32; off>0; off>>=1) s += __shfl_down(s, off);
  if (ln==0) red2[wv] = s;
  __syncthreads();
  s = red2[0]+red2[1]+red2[2]+red2[3];
  float lse = mx + __logf(s);
  #pragma unroll
  for (int i=0;i<40;i++){
    int c = threadIdx.x + (i<<8);
    if (c < NTOK) p[c] = v[i] - lse;
  }
}

__global__ void k_copy(const float* __restrict__ src, float* __restrict__ dst, int n){
  int i = blockIdx.x*blockDim.x + threadIdx.x;
  if (i < n) dst[i] = src[i];
}

// ---------------- launch ----------------

extern "C" void kernel_launch(void* const* d_in, const int* in_sizes, int n_in,
                              void* d_out, int out_size, void* d_ws, size_t ws_size,
                              hipStream_t stream) {
  const int*   tok  = (const int*)d_in[0];
  const float* h0   = (const float*)d_in[1];
  const float* encw = (const float*)d_in[2];
  const float* W0   = (const float*)d_in[3];
  const float* Ws   = (const float*)d_in[4];
  const float* decb = (const float*)d_in[5];
  float* out = (float*)d_out;

  char* w = (char*)d_ws;
  unsigned short* Wt      = (unsigned short*)w; w += (size_t)10*WMAT*2;      // 41,943,040
  unsigned short* encw_bf = (unsigned short*)w; w += (size_t)NTOK*NHID*2;    // 20,480,000
  unsigned short* h0_bf   = (unsigned short*)w; w += (size_t)BN*2;           // 65,536
  unsigned short* hid_bf  = (unsigned short*)w; w += (size_t)TT*BN*2;        // 8,388,608
  float*          st_f    = (float*)w;          w += (size_t)9*BN*4;         // 1,179,648
  unsigned short* st_bf   = (unsigned short*)w; w += (size_t)9*BN*2;         // 589,824
  float*          hbuf    = (float*)w;          w += (size_t)2*BN*4;         // 262,144

  // prep: transpose weights to bf16 (n,k); convert encW and h0 to bf16
  k_transpose_cvt<<<dim3(64,32,10), 256, 0, stream>>>(W0, Ws, Wt);
  k_cvt<<<4096, 256, 0, stream>>>(encw, encw_bf, NTOK*NHID);
  k_cvt<<<128, 256, 0, stream>>>(h0, h0_bf, BN);

  for (int t = 0; t < TT; ++t) {
    const unsigned short* hprev_bf = t ? (hid_bf + (size_t)(t-1)*BN) : h0_bf;
    const float*          hprev_f  = t ? (hbuf + (size_t)((t-1)&1)*BN) : h0;
    float*          hout_f  = hbuf + (size_t)(t&1)*BN;
    unsigned short* hout_bf = hid_bf + (size_t)t*BN;
    k_init <<<64, 64, 0, stream>>>(tok + t*BB, encw_bf, Wt, hprev_bf, hprev_f, st_f, st_bf);
    k_edges<<<64, 64, 0, stream>>>(Wt, st_f, st_bf, 0,0,0, 0,0,0, 0,0,0);   // e0: sig, pred0
    k_edges<<<192,64, 0, stream>>>(Wt, st_f, st_bf, 1,1,1, 2,1,1, 3,1,3);   // e1 relu,e2 relu,e3 id (pred1)
    k_edges<<<128,64, 0, stream>>>(Wt, st_f, st_bf, 4,2,2, 6,3,2, 0,0,0);   // e4 tanh p2, e6 tanh p3
    k_last <<<64, 64, 0, stream>>>(Wt, st_f, st_bf, hout_f, hout_bf);
  }

  // decoder + log_softmax + h_last
  k_decoder<<<dim3(157,64), 256, 0, stream>>>(hid_bf, encw_bf, out);
  k_logsoftmax<<<TT*BB, 256, 0, stream>>>(out, decb);
  k_copy<<<128, 256, 0, stream>>>(hbuf + (size_t)((TT-1)&1)*BN, out + (size_t)TT*BB*NTOK, BN);
}

// Round 2
// 9891.491 us; speedup vs baseline: 1.2656x; 1.2656x over previous
//
#include <hip/hip_runtime.h>
#include <cmath>

#define NHID 1024
#define NTOK 10000
#define TT 128
#define BB 32
#define BN (BB*NHID)            // elems per (B,NHID) state
#define WMAT (2048*1024)        // elems per transposed weight matrix

typedef __attribute__((ext_vector_type(8))) short s8v;   // 8 x bf16 raw
typedef __attribute__((ext_vector_type(4))) float f4v;   // MFMA accumulator

#define MFMA(a,b,c) __builtin_amdgcn_mfma_f32_16x16x32_bf16(a,b,c,0,0,0)

__device__ __forceinline__ float sigf(float x){ return 1.f/(1.f+__expf(-x)); }
__device__ __forceinline__ float actf(int a, float h){
  switch(a){ case 0: return sigf(h); case 1: return fmaxf(h,0.f);
             case 2: return tanhf(h); default: return h; }
}
__device__ __forceinline__ unsigned short f2bf(float x){
  union { float f; unsigned u; } v; v.f = x;
  unsigned r = v.u + 0x7fffu + ((v.u >> 16) & 1u);
  return (unsigned short)(r >> 16);
}

// ---------------- prep kernels ----------------

__global__ __launch_bounds__(256) void k_transpose_cvt(
    const float* __restrict__ W0, const float* __restrict__ Ws,
    unsigned short* __restrict__ dstAll)
{
  int z = blockIdx.z;
  const float* src = (z==0) ? W0 : (z==1) ? (W0 + (size_t)1024*2048)
                                          : (Ws + (size_t)(z-2)*1024*2048);
  unsigned short* dst = dstAll + (size_t)z*WMAT;
  __shared__ float tile[32][33];
  int n0 = blockIdx.x*32;
  int k0 = blockIdx.y*32;
  int tx = threadIdx.x & 31, ty = threadIdx.x >> 5;
  #pragma unroll
  for (int i=0;i<4;i++){
    int k = k0 + ty + i*8;
    tile[ty + i*8][tx] = src[(size_t)k*2048 + n0 + tx];
  }
  __syncthreads();
  #pragma unroll
  for (int i=0;i<4;i++){
    int n = n0 + ty + i*8;
    dst[(size_t)n*1024 + k0 + tx] = f2bf(tile[tx][ty + i*8]);
  }
}

__global__ void k_cvt(const float* __restrict__ src, unsigned short* __restrict__ dst, int n){
  int i = blockIdx.x*blockDim.x + threadIdx.x;
  int stride = gridDim.x*blockDim.x;
  for (; i < n; i += stride) dst[i] = f2bf(src[i]);
}

__global__ void k_zero(unsigned* __restrict__ p){
  if (threadIdx.x < 16) p[threadIdx.x] = 0u;
}

// ---------------- persistent recurrence kernel ----------------
// grid = 256 WGs x 256 threads (4 waves), 1 per CU, all co-resident.
// counters: cnt[s] = #tiles of state s written (monotonic over steps); cnt[8] = h.

__device__ __forceinline__ void wg_wait(unsigned* c, unsigned target){
  if (threadIdx.x == 0) {
    while (__hip_atomic_load(c, __ATOMIC_RELAXED, __HIP_MEMORY_SCOPE_AGENT) < target)
      __builtin_amdgcn_s_sleep(1);
    (void)__hip_atomic_load(c, __ATOMIC_ACQUIRE, __HIP_MEMORY_SCOPE_AGENT); // inv L1/L2
  }
  __syncthreads();
}
__device__ __forceinline__ void wg_signal(unsigned* c){
  __syncthreads();   // per-wave vmcnt(0) drain before barrier => stores visible
  if (threadIdx.x == 0)
    __hip_atomic_fetch_add(c, 1u, __ATOMIC_RELEASE, __HIP_MEMORY_SCOPE_AGENT);
}

// one edge task: 16 paired cols (tile j0), K=1024 split 4 ways over waves
__device__ __forceinline__ void do_edge(
    const unsigned short* __restrict__ Wt, float* __restrict__ st_f,
    unsigned short* __restrict__ st_bf, float* __restrict__ red,
    unsigned* __restrict__ cnt, int z, int pred, int outs, int act,
    int j0, unsigned target)
{
  wg_wait(&cnt[pred], target);
  int tid = threadIdx.x, wave = tid>>6, lane = tid&63, q = lane>>4, r = lane&15;
  const unsigned short* spb = st_bf + (size_t)pred*BN;
  int kb = wave*256;
  const s8v* ap0 = (const s8v*)(spb + (size_t)r*NHID + kb);
  const s8v* ap1 = (const s8v*)(spb + (size_t)(16+r)*NHID + kb);
  const unsigned short* wz = Wt + (size_t)z*WMAT;
  const s8v* bc = (const s8v*)(wz + (size_t)(j0+r)*1024 + kb);
  const s8v* bh = (const s8v*)(wz + (size_t)(1024+j0+r)*1024 + kb);
  f4v zz = {0.f,0.f,0.f,0.f};
  f4v aC0=zz,aC1=zz,aH0=zz,aH1=zz;
  #pragma unroll
  for (int v=q; v<32; v+=4){
    s8v a0=ap0[v], a1=ap1[v], b0=bc[v], b1=bh[v];
    aC0=MFMA(a0,b0,aC0); aC1=MFMA(a1,b0,aC1);
    aH0=MFMA(a0,b1,aH0); aH1=MFMA(a1,b1,aH1);
  }
  #pragma unroll
  for (int i=0;i<4;i++){
    red[((wave*4+0)*32 + q*4+i)*16 + r]    = aC0[i];
    red[((wave*4+0)*32 + 16+q*4+i)*16 + r] = aC1[i];
    red[((wave*4+1)*32 + q*4+i)*16 + r]    = aH0[i];
    red[((wave*4+1)*32 + 16+q*4+i)*16 + r] = aH1[i];
  }
  __syncthreads();
  int row = tid>>3, col = (tid&7)*2;
  float cs0=0,cs1=0,hs0=0,hs1=0;
  #pragma unroll
  for (int w2=0; w2<4; w2++){
    cs0 += red[((w2*4+0)*32+row)*16+col];
    cs1 += red[((w2*4+0)*32+row)*16+col+1];
    hs0 += red[((w2*4+1)*32+row)*16+col];
    hs1 += red[((w2*4+1)*32+row)*16+col+1];
  }
  size_t off = (size_t)row*NHID + j0 + col;
  const float* spf = st_f + (size_t)pred*BN;
  float sp0 = spf[off], sp1 = spf[off+1];
  float v0 = sp0 + sigf(cs0)*(actf(act,hs0) - sp0);
  float v1 = sp1 + sigf(cs1)*(actf(act,hs1) - sp1);
  __hip_atomic_store(&st_f[(size_t)outs*BN+off],   v0, __ATOMIC_RELAXED, __HIP_MEMORY_SCOPE_AGENT);
  __hip_atomic_store(&st_f[(size_t)outs*BN+off+1], v1, __ATOMIC_RELAXED, __HIP_MEMORY_SCOPE_AGENT);
  unsigned pk = (unsigned)f2bf(v0) | ((unsigned)f2bf(v1)<<16);
  __hip_atomic_store((unsigned*)(st_bf + (size_t)outs*BN + off), pk,
                     __ATOMIC_RELAXED, __HIP_MEMORY_SCOPE_AGENT);
  wg_signal(&cnt[outs]);
}

__global__ __launch_bounds__(256) void k_recur(
    const int* __restrict__ tok, const float* __restrict__ h0f,
    const unsigned short* __restrict__ encb,
    const unsigned short* __restrict__ Wt,
    const unsigned short* __restrict__ h0b,
    float* __restrict__ st_f, unsigned short* __restrict__ st_bf,
    float* __restrict__ h_f, unsigned short* __restrict__ h_bf,
    unsigned short* __restrict__ hid_bf, unsigned* __restrict__ cnt)
{
  __shared__ float red[4*4*32*16];   // 32 KB: [wave][ch up to 4][row 32][col 16]
  int wg = blockIdx.x, grp = wg >> 6, tile = wg & 63;
  int tid = threadIdx.x, wave = tid>>6, lane = tid&63, q = lane>>4, r = lane&15;
  int j0 = tile * 16;

  for (int t = 0; t < TT; ++t) {
    unsigned tgt = 64u*(t+1);
    if (grp == 0) {
      // ---- L1: init (K=2048: waves 0-1 take x half, 2-3 take h half) ----
      if (t) wg_wait(&cnt[8], 64u*t);
      {
        const unsigned short* hb = t ? h_bf : h0b;
        int kb = wave * 512;
        const unsigned short *arow0, *arow1;
        if (wave < 2) {
          arow0 = encb + (size_t)tok[t*BB + r]*NHID + kb;
          arow1 = encb + (size_t)tok[t*BB + 16 + r]*NHID + kb;
        } else {
          arow0 = hb + (size_t)r*NHID + (kb - 1024);
          arow1 = hb + (size_t)(16+r)*NHID + (kb - 1024);
        }
        const unsigned short* wz = Wt + (size_t)(wave>>1)*WMAT;
        int kloc = (wave & 1) * 512;
        const s8v* ap0 = (const s8v*)arow0;
        const s8v* ap1 = (const s8v*)arow1;
        const s8v* bc = (const s8v*)(wz + (size_t)(j0+r)*1024 + kloc);
        const s8v* bh = (const s8v*)(wz + (size_t)(1024+j0+r)*1024 + kloc);
        f4v zz = {0.f,0.f,0.f,0.f};
        f4v aC0=zz,aC1=zz,aH0=zz,aH1=zz;
        #pragma unroll
        for (int v=q; v<64; v+=4){
          s8v a0=ap0[v], a1=ap1[v], b0=bc[v], b1=bh[v];
          aC0=MFMA(a0,b0,aC0); aC1=MFMA(a1,b0,aC1);
          aH0=MFMA(a0,b1,aH0); aH1=MFMA(a1,b1,aH1);
        }
        #pragma unroll
        for (int i=0;i<4;i++){
          red[((wave*4+0)*32 + q*4+i)*16 + r]    = aC0[i];
          red[((wave*4+0)*32 + 16+q*4+i)*16 + r] = aC1[i];
          red[((wave*4+1)*32 + q*4+i)*16 + r]    = aH0[i];
          red[((wave*4+1)*32 + 16+q*4+i)*16 + r] = aH1[i];
        }
        __syncthreads();
        int row = tid>>3, col = (tid&7)*2;
        float cs0=0,cs1=0,hs0=0,hs1=0;
        #pragma unroll
        for (int w2=0; w2<4; w2++){
          cs0 += red[((w2*4+0)*32+row)*16+col];
          cs1 += red[((w2*4+0)*32+row)*16+col+1];
          hs0 += red[((w2*4+1)*32+row)*16+col];
          hs1 += red[((w2*4+1)*32+row)*16+col+1];
        }
        const float* hfb = t ? h_f : h0f;
        size_t off = (size_t)row*NHID + j0 + col;
        float hp0 = hfb[off], hp1 = hfb[off+1];
        float v0 = hp0 + sigf(cs0)*(tanhf(hs0)-hp0);
        float v1 = hp1 + sigf(cs1)*(tanhf(hs1)-hp1);
        __hip_atomic_store(&st_f[off],   v0, __ATOMIC_RELAXED, __HIP_MEMORY_SCOPE_AGENT);
        __hip_atomic_store(&st_f[off+1], v1, __ATOMIC_RELAXED, __HIP_MEMORY_SCOPE_AGENT);
        unsigned pk = (unsigned)f2bf(v0) | ((unsigned)f2bf(v1)<<16);
        __hip_atomic_store((unsigned*)(st_bf + off), pk,
                           __ATOMIC_RELAXED, __HIP_MEMORY_SCOPE_AGENT);
        wg_signal(&cnt[0]);
      }
      // ---- L3: e3 (identity, pred s1, out s4) ----
      do_edge(Wt, st_f, st_bf, red, cnt, /*z=*/5, /*pred=*/1, /*outs=*/4, /*act=*/3, j0, tgt);
    } else if (grp == 1) {
      // ---- L2: e0 (sigmoid, pred s0, out s1) ----
      do_edge(Wt, st_f, st_bf, red, cnt, 2, 0, 1, 0, j0, tgt);
      // ---- L4: e4 (tanh, pred s2, out s5) ----
      do_edge(Wt, st_f, st_bf, red, cnt, 6, 2, 5, 2, j0, tgt);
    } else if (grp == 2) {
      // ---- L3: e1 (relu, pred s1, out s2) ----
      do_edge(Wt, st_f, st_bf, red, cnt, 3, 1, 2, 1, j0, tgt);
      // ---- L4: e6 (tanh, pred s3, out s7) ----
      do_edge(Wt, st_f, st_bf, red, cnt, 8, 3, 7, 2, j0, tgt);
    } else {
      // ---- L3: e2 (relu, pred s1, out s3) ----
      do_edge(Wt, st_f, st_bf, red, cnt, 4, 1, 3, 1, j0, tgt);
      // ---- L5: fused e5 (sigmoid) + e7 (relu), pred s5; compute mean h ----
      wg_wait(&cnt[4], tgt);
      wg_wait(&cnt[5], tgt);
      wg_wait(&cnt[7], tgt);
      {
        const unsigned short* spb = st_bf + (size_t)5*BN;
        int kb = wave*256;
        const s8v* ap0 = (const s8v*)(spb + (size_t)r*NHID + kb);
        const s8v* ap1 = (const s8v*)(spb + (size_t)(16+r)*NHID + kb);
        const unsigned short* W5 = Wt + (size_t)7*WMAT;
        const unsigned short* W7 = Wt + (size_t)9*WMAT;
        const s8v* b5c = (const s8v*)(W5 + (size_t)(j0+r)*1024 + kb);
        const s8v* b5h = (const s8v*)(W5 + (size_t)(1024+j0+r)*1024 + kb);
        const s8v* b7c = (const s8v*)(W7 + (size_t)(j0+r)*1024 + kb);
        const s8v* b7h = (const s8v*)(W7 + (size_t)(1024+j0+r)*1024 + kb);
        f4v zz = {0.f,0.f,0.f,0.f};
        f4v c50=zz,c51=zz,h50=zz,h51=zz,c70=zz,c71=zz,h70=zz,h71=zz;
        #pragma unroll
        for (int v=q; v<32; v+=4){
          s8v a0=ap0[v], a1=ap1[v];
          s8v x5c=b5c[v], x5h=b5h[v], x7c=b7c[v], x7h=b7h[v];
          c50=MFMA(a0,x5c,c50); c51=MFMA(a1,x5c,c51);
          h50=MFMA(a0,x5h,h50); h51=MFMA(a1,x5h,h51);
          c70=MFMA(a0,x7c,c70); c71=MFMA(a1,x7c,c71);
          h70=MFMA(a0,x7h,h70); h71=MFMA(a1,x7h,h71);
        }
        #pragma unroll
        for (int i=0;i<4;i++){
          red[((wave*4+0)*32 + q*4+i)*16 + r]    = c50[i];
          red[((wave*4+0)*32 + 16+q*4+i)*16 + r] = c51[i];
          red[((wave*4+1)*32 + q*4+i)*16 + r]    = h50[i];
          red[((wave*4+1)*32 + 16+q*4+i)*16 + r] = h51[i];
          red[((wave*4+2)*32 + q*4+i)*16 + r]    = c70[i];
          red[((wave*4+2)*32 + 16+q*4+i)*16 + r] = c71[i];
          red[((wave*4+3)*32 + q*4+i)*16 + r]    = h70[i];
          red[((wave*4+3)*32 + 16+q*4+i)*16 + r] = h71[i];
        }
        __syncthreads();
        int row = tid>>3, col = (tid&7)*2;
        float a5c[2]={0,0}, a5h[2]={0,0}, a7c[2]={0,0}, a7h[2]={0,0};
        #pragma unroll
        for (int w2=0; w2<4; w2++){
          #pragma unroll
          for (int u=0; u<2; u++){
            a5c[u] += red[((w2*4+0)*32+row)*16+col+u];
            a5h[u] += red[((w2*4+1)*32+row)*16+col+u];
            a7c[u] += red[((w2*4+2)*32+row)*16+col+u];
            a7h[u] += red[((w2*4+3)*32+row)*16+col+u];
          }
        }
        size_t off = (size_t)row*NHID + j0 + col;
        float hv[2];
        #pragma unroll
        for (int u=0; u<2; u++){
          float s5j = st_f[(size_t)5*BN + off + u];
          float s6 = s5j + sigf(a5c[u])*(sigf(a5h[u]) - s5j);
          float s8 = s5j + sigf(a7c[u])*(fmaxf(a7h[u],0.f) - s5j);
          float sum = st_f[(size_t)1*BN+off+u] + st_f[(size_t)2*BN+off+u]
                    + st_f[(size_t)3*BN+off+u] + st_f[(size_t)4*BN+off+u]
                    + s5j + s6 + st_f[(size_t)7*BN+off+u] + s8;
          hv[u] = 0.125f * sum;
          __hip_atomic_store(&h_f[off+u], hv[u], __ATOMIC_RELAXED, __HIP_MEMORY_SCOPE_AGENT);
        }
        unsigned pk = (unsigned)f2bf(hv[0]) | ((unsigned)f2bf(hv[1])<<16);
        __hip_atomic_store((unsigned*)(h_bf + off), pk,
                           __ATOMIC_RELAXED, __HIP_MEMORY_SCOPE_AGENT);
        *(unsigned*)(hid_bf + (size_t)t*BN + off) = pk;   // consumed post-kernel
        wg_signal(&cnt[8]);
      }
    }
  }
}

// ---------------- decoder ----------------

__global__ __launch_bounds__(256) void k_decoder(
    const unsigned short* __restrict__ Hb, const unsigned short* __restrict__ Wb,
    float* __restrict__ out)
{
  int wave = threadIdx.x >> 6, lane = threadIdx.x & 63;
  int q = lane >> 4, r = lane & 15;
  int bm = blockIdx.y*64 + (wave>>1)*32;
  int bn = blockIdx.x*64 + (wave&1)*32;
  f4v z = {0.f,0.f,0.f,0.f};
  f4v acc00=z, acc01=z, acc10=z, acc11=z;
  const s8v* a0p = (const s8v*)(Hb + (size_t)(bm + r)*NHID);
  const s8v* a1p = (const s8v*)(Hb + (size_t)(bm + 16 + r)*NHID);
  int n0 = bn + r, n1 = bn + 16 + r;
  const s8v* b0p = (const s8v*)(Wb + (size_t)(n0 < NTOK ? n0 : 0)*NHID);
  const s8v* b1p = (const s8v*)(Wb + (size_t)(n1 < NTOK ? n1 : 0)*NHID);
  #pragma unroll 4
  for (int v = q; v < 128; v += 4) {
    s8v a0 = a0p[v], a1 = a1p[v], b0 = b0p[v], b1 = b1p[v];
    acc00 = MFMA(a0, b0, acc00); acc10 = MFMA(a1, b0, acc10);
    acc01 = MFMA(a0, b1, acc01); acc11 = MFMA(a1, b1, acc11);
  }
  #pragma unroll
  for (int ni=0; ni<2; ni++){
    int col = bn + ni*16 + r;
    if (col >= NTOK) continue;
    #pragma unroll
    for (int mi=0; mi<2; mi++){
      f4v a = (mi==0) ? (ni==0 ? acc00 : acc01) : (ni==0 ? acc10 : acc11);
      #pragma unroll
      for (int t4=0; t4<4; t4++){
        int row = bm + mi*16 + q*4 + t4;
        out[(size_t)row*NTOK + col] = a[t4];
      }
    }
  }
}

__global__ __launch_bounds__(256) void k_logsoftmax(
    float* __restrict__ logits, const float* __restrict__ bias)
{
  size_t row = blockIdx.x;
  float* p = logits + row * NTOK;
  float v[40];
  float mx = -1e30f;
  #pragma unroll
  for (int i=0;i<40;i++){
    int c = threadIdx.x + (i<<8);
    float x = (c < NTOK) ? (p[c] + bias[c]) : -1e30f;
    v[i] = x; mx = fmaxf(mx, x);
  }
  #pragma unroll
  for (int off=32; off>0; off>>=1) mx = fmaxf(mx, __shfl_down(mx, off));
  __shared__ float red[4], red2[4];
  int wv = threadIdx.x>>6, ln = threadIdx.x&63;
  if (ln==0) red[wv] = mx;
  __syncthreads();
  mx = fmaxf(fmaxf(red[0],red[1]), fmaxf(red[2],red[3]));
  float s = 0.f;
  #pragma unroll
  for (int i=0;i<40;i++) s += __expf(v[i] - mx);
  #pragma unroll
  for (int off=32; off>0; off>>=1) s += __shfl_down(s, off);
  if (ln==0) red2[wv] = s;
  __syncthreads();
  s = red2[0]+red2[1]+red2[2]+red2[3];
  float lse = mx + __logf(s);
  #pragma unroll
  for (int i=0;i<40;i++){
    int c = threadIdx.x + (i<<8);
    if (c < NTOK) p[c] = v[i] - lse;
  }
}

__global__ void k_copy(const float* __restrict__ src, float* __restrict__ dst, int n){
  int i = blockIdx.x*blockDim.x + threadIdx.x;
  if (i < n) dst[i] = src[i];
}

// ---------------- launch ----------------

extern "C" void kernel_launch(void* const* d_in, const int* in_sizes, int n_in,
                              void* d_out, int out_size, void* d_ws, size_t ws_size,
                              hipStream_t stream) {
  const int*   tok  = (const int*)d_in[0];
  const float* h0   = (const float*)d_in[1];
  const float* encw = (const float*)d_in[2];
  const float* W0   = (const float*)d_in[3];
  const float* Ws   = (const float*)d_in[4];
  const float* decb = (const float*)d_in[5];
  float* out = (float*)d_out;

  char* w = (char*)d_ws;
  unsigned short* Wt      = (unsigned short*)w; w += (size_t)10*WMAT*2;
  unsigned short* encw_bf = (unsigned short*)w; w += (size_t)NTOK*NHID*2;
  unsigned short* h0_bf   = (unsigned short*)w; w += (size_t)BN*2;
  unsigned short* hid_bf  = (unsigned short*)w; w += (size_t)TT*BN*2;
  float*          st_f    = (float*)w;          w += (size_t)9*BN*4;
  unsigned short* st_bf   = (unsigned short*)w; w += (size_t)9*BN*2;
  float*          h_f     = (float*)w;          w += (size_t)BN*4;
  unsigned short* h_bf    = (unsigned short*)w; w += (size_t)BN*2;
  unsigned*       cnt     = (unsigned*)w;       w += 64;

  k_zero<<<1, 64, 0, stream>>>(cnt);
  k_transpose_cvt<<<dim3(64,32,10), 256, 0, stream>>>(W0, Ws, Wt);
  k_cvt<<<4096, 256, 0, stream>>>(encw, encw_bf, NTOK*NHID);
  k_cvt<<<128, 256, 0, stream>>>(h0, h0_bf, BN);

  k_recur<<<256, 256, 0, stream>>>(tok, h0, encw_bf, Wt, h0_bf,
                                   st_f, st_bf, h_f, h_bf, hid_bf, cnt);

  k_decoder<<<dim3(157,64), 256, 0, stream>>>(hid_bf, encw_bf, out);
  k_logsoftmax<<<TT*BB, 256, 0, stream>>>(out, decb);
  k_copy<<<128, 256, 0, stream>>>(h_f, out + (size_t)TT*BB*NTOK, BN);
}